// Round 1
// baseline (2504.872 us; speedup 1.0000x reference)
//
#include <hip/hip_runtime.h>

#define MSG 64

// T[a][m] = bias[m] + sum_k emb[a][k] * W[k][m]   (W already offset to start row, ld=64)
__global__ void table_gemm_kernel(const float* __restrict__ emb, int K,
                                  const float* __restrict__ W,
                                  const float* __restrict__ bias,
                                  float* __restrict__ T, int rows) {
    int t = blockIdx.x * blockDim.x + threadIdx.x;
    if (t >= rows * MSG) return;
    int a = t >> 6, m = t & 63;
    float s = bias ? bias[m] : 0.0f;
    for (int k = 0; k < K; ++k) s = fmaf(emb[a * K + k], W[k * MSG + m], s);
    T[t] = s;
}

// Per edge e, lane i: m = relu(tAtom[x[src]][i] + tBond[ea][i] (+ agg2[src][i]))
// then atomicAdd into out[dst][i].  One 64-lane wave row per edge.
__global__ void edge_kernel(const int* __restrict__ x, const int* __restrict__ eattr,
                            const int* __restrict__ ei, int E,
                            const float* __restrict__ tAtom, const float* __restrict__ tBond,
                            const float* __restrict__ agg2,   // null for pass 0
                            float* __restrict__ out) {
    long long t = (long long)blockIdx.x * blockDim.x + threadIdx.x;
    long long e = t >> 6;
    if (e >= E) return;
    int i = (int)(t & 63);
    int src = ei[e];
    int dst = ei[E + e];
    int b   = eattr[e];
    float m = tAtom[(long long)x[src] * MSG + i] + tBond[b * MSG + i];
    if (agg2) m += agg2[(long long)src * MSG + i];
    m = fmaxf(m, 0.0f);
    atomicAdd(&out[(long long)dst * MSG + i], m);
}

// agg2 = A @ W  (A: [N,64], W: [64,64] row-major).  4 nodes per 256-thread block.
__global__ void node_gemm_kernel(const float* __restrict__ A, const float* __restrict__ W,
                                 float* __restrict__ agg2, int N) {
    __shared__ float Ws[64 * 64];
    for (int idx = threadIdx.x; idx < 64 * 64; idx += blockDim.x) Ws[idx] = W[idx];
    __syncthreads();
    long long t = (long long)blockIdx.x * blockDim.x + threadIdx.x;
    long long n = t >> 6;
    if (n >= N) return;
    int m = (int)(t & 63);
    const float* row = &A[n * 64];
    float s = 0.0f;
#pragma unroll
    for (int k = 0; k < 64; ++k) s = fmaf(row[k], Ws[k * 64 + m], s);
    agg2[n * 64 + m] = s;
}

__global__ void mol_scatter_kernel(const float* __restrict__ ns, const int* __restrict__ batch,
                                   float* __restrict__ mol, int N) {
    long long t = (long long)blockIdx.x * blockDim.x + threadIdx.x;
    long long n = t >> 6;
    if (n >= N) return;
    int i = (int)(t & 63);
    atomicAdd(&mol[(long long)batch[n] * MSG + i], ns[n * MSG + i]);
}

// One block (128 threads) per molecule: h = relu(mol@W1+b1); out = h@W2+b2
__global__ void head_kernel(const float* __restrict__ mol, const float* __restrict__ W1,
                            const float* __restrict__ b1, const float* __restrict__ W2,
                            const float* __restrict__ b2, float* __restrict__ out) {
    int g = blockIdx.x;
    int j = threadIdx.x;   // 0..127
    float s = b1[j];
#pragma unroll
    for (int k = 0; k < 64; ++k) s = fmaf(mol[g * 64 + k], W1[k * 128 + j], s);
    s = fmaxf(s, 0.0f) * W2[j];
    __shared__ float red[128];
    red[j] = s;
    __syncthreads();
    for (int off = 64; off > 0; off >>= 1) {
        if (j < off) red[j] += red[j + off];
        __syncthreads();
    }
    if (j == 0) out[g] = red[0] + b2[0];
}

extern "C" void kernel_launch(void* const* d_in, const int* in_sizes, int n_in,
                              void* d_out, int out_size, void* d_ws, size_t ws_size,
                              hipStream_t stream) {
    const int*   x          = (const int*)d_in[0];
    const int*   eattr      = (const int*)d_in[1];
    const int*   ei         = (const int*)d_in[2];
    const int*   batch      = (const int*)d_in[3];
    const float* atom_table = (const float*)d_in[4];
    const float* bond_table = (const float*)d_in[5];
    const float* Wi         = (const float*)d_in[6];
    const float* bi         = (const float*)d_in[7];
    const float* Wu         = (const float*)d_in[8];
    const float* bu         = (const float*)d_in[9];
    const float* W1         = (const float*)d_in[10];
    const float* b1         = (const float*)d_in[11];
    const float* W2         = (const float*)d_in[12];
    const float* b2         = (const float*)d_in[13];

    const int N  = in_sizes[0];          // 100000 nodes
    const int E  = in_sizes[1];          // 1.6M edges
    const int M  = out_size;             // 2048 mols
    const int AR = in_sizes[4] / 64;     // 119 atom rows
    const int BR = in_sizes[5] / 16;     // 4 bond rows

    char* ws = (char*)d_ws;
    size_t off = 0;
    auto alloc = [&](size_t bytes) -> void* {
        void* p = ws + off;
        off = (off + bytes + 255) & ~(size_t)255;
        return p;
    };
    float* A    = (float*)alloc((size_t)N * MSG * 4);
    float* B    = (float*)alloc((size_t)N * MSG * 4);
    float* agg2 = (float*)alloc((size_t)N * MSG * 4);
    float* tAi  = (float*)alloc((size_t)AR * MSG * 4);
    float* tBi  = (float*)alloc((size_t)BR * MSG * 4);
    float* tAu  = (float*)alloc((size_t)AR * MSG * 4);
    float* tBu  = (float*)alloc((size_t)BR * MSG * 4);
    float* mol  = (float*)alloc((size_t)M * MSG * 4);
    (void)ws_size; (void)n_in;

    // Tiny table GEMMs: fold biases into the bond tables.
    table_gemm_kernel<<<(AR * MSG + 255) / 256, 256, 0, stream>>>(atom_table, 64, Wi,            nullptr, tAi, AR);
    table_gemm_kernel<<<1, 256, 0, stream>>>(bond_table, 16, Wi + 64 * MSG, bi, tBi, BR);
    table_gemm_kernel<<<(AR * MSG + 255) / 256, 256, 0, stream>>>(atom_table, 64, Wu,            nullptr, tAu, AR);
    table_gemm_kernel<<<1, 256, 0, stream>>>(bond_table, 16, Wu + 64 * MSG, bu, tBu, BR);

    const int eblocks = (int)(((long long)E * MSG + 255) / 256);
    const int nblocks = (int)(((long long)N * MSG + 255) / 256);

    // Pass 0: msg0 = relu(ab@Wi+bi) scattered by dst -> A = agg_1
    hipMemsetAsync(A, 0, (size_t)N * MSG * 4, stream);
    edge_kernel<<<eblocks, 256, 0, stream>>>(x, eattr, ei, E, tAi, tBi, nullptr, A);

    // 4 message passes
    for (int p = 0; p < 4; ++p) {
        node_gemm_kernel<<<nblocks, 256, 0, stream>>>(A, Wu + 80 * MSG, agg2, N);
        hipMemsetAsync(B, 0, (size_t)N * MSG * 4, stream);
        edge_kernel<<<eblocks, 256, 0, stream>>>(x, eattr, ei, E, tAu, tBu, agg2, B);
        float* tmp = A; A = B; B = tmp;
    }
    // A now holds node_state = segment_sum(msg_4, dst)

    hipMemsetAsync(mol, 0, (size_t)M * MSG * 4, stream);
    mol_scatter_kernel<<<nblocks, 256, 0, stream>>>(A, batch, mol, N);

    head_kernel<<<M, 128, 0, stream>>>(mol, W1, b1, W2, b2, (float*)d_out);
}

// Round 2
// 809.519 us; speedup vs baseline: 3.0943x; 3.0943x over previous
//
#include <hip/hip_runtime.h>

#define MSG 64
#define NCOMBO 476   // 119 atom ids * 4 bond ids

// tAB[c][i] = bias[i] + atom[c>>2] @ W[0:64] + bond[c&3] @ W[64:80]   (W ld=64)
__global__ void build_tab_kernel(const float* __restrict__ atom, const float* __restrict__ bond,
                                 const float* __restrict__ W, const float* __restrict__ bias,
                                 float* __restrict__ tAB) {
    int t = blockIdx.x * blockDim.x + threadIdx.x;
    if (t >= NCOMBO * MSG) return;
    int i = t & 63, c = t >> 6, xa = c >> 2, ea = c & 3;
    float s = bias[i];
    for (int k = 0; k < 64; ++k) s = fmaf(atom[xa * 64 + k], W[k * 64 + i], s);
    for (int k = 0; k < 16; ++k) s = fmaf(bond[ea * 16 + k], W[(64 + k) * 64 + i], s);
    tAB[t] = s;
}

__global__ void hist_kernel(const int* __restrict__ ei, int E, int* __restrict__ cnt) {
    int e = blockIdx.x * blockDim.x + threadIdx.x;
    if (e < E) atomicAdd(&cnt[ei[E + e]], 1);
}

// block-level inclusive scan (1024/block) + block sums
__global__ void scan1_kernel(const int* __restrict__ cnt, int* __restrict__ incl,
                             int* __restrict__ bsum, int N) {
    int i = blockIdx.x * 1024 + threadIdx.x;
    int v = (i < N) ? cnt[i] : 0;
    int lane = threadIdx.x & 63, w = threadIdx.x >> 6;
    int s = v;
    for (int off = 1; off < 64; off <<= 1) { int t = __shfl_up(s, off); if (lane >= off) s += t; }
    __shared__ int wsum[16];
    if (lane == 63) wsum[w] = s;
    __syncthreads();
    if (w == 0 && lane < 16) {
        int t = wsum[lane];
        for (int off = 1; off < 16; off <<= 1) { int u = __shfl_up(t, off); if (lane >= off) t += u; }
        wsum[lane] = t;
    }
    __syncthreads();
    if (w > 0) s += wsum[w - 1];
    if (i < N) incl[i] = s;
    if (threadIdx.x == 1023) bsum[blockIdx.x] = s;
}

__global__ void scan2_kernel(int* __restrict__ bsum, int nb) {
    if (threadIdx.x == 0 && blockIdx.x == 0) {
        int run = 0;
        for (int b = 0; b < nb; ++b) { int t = bsum[b]; bsum[b] = run; run += t; }
    }
}

__global__ void scan3_kernel(const int* __restrict__ incl, const int* __restrict__ bsum,
                             int* __restrict__ off, int N) {
    int i = blockIdx.x * 1024 + threadIdx.x;
    if (i < N) off[i + 1] = incl[i] + bsum[blockIdx.x];
    if (i == 0) off[0] = 0;
}

// packed[pos] = src | combo<<17, pos claimed via cursor (cursor pre-loaded with CSR offsets)
__global__ void scatter_kernel(const int* __restrict__ ei, const int* __restrict__ x,
                               const int* __restrict__ eattr, int E,
                               int* __restrict__ cursor, unsigned* __restrict__ packed) {
    int e = blockIdx.x * blockDim.x + threadIdx.x;
    if (e >= E) return;
    int s = ei[e], d = ei[E + e];
    int p = atomicAdd(&cursor[d], 1);
    packed[p] = (unsigned)s | ((unsigned)(x[s] * 4 + eattr[e]) << 17);
}

// One wave per node: acc[i] = sum_{e in-edges} relu(tAB[combo][i] + agg2[src][i]).
// MODE 0: no agg2, fused epilogue GEMM; MODE 1: agg2 + fused GEMM; MODE 2: agg2, raw out.
template <int MODE>
__global__ __launch_bounds__(256) void gather_kernel(
    const unsigned* __restrict__ packed, const int* __restrict__ off,
    const float* __restrict__ tAB, const float* __restrict__ agg2,
    const float* __restrict__ Wagg, float* __restrict__ out, int N)
{
    __shared__ float Ws[64 * 64];
    __shared__ float rowbuf[4][64];
    if (MODE < 2)
        for (int idx = threadIdx.x; idx < 64 * 64; idx += 256) Ws[idx] = Wagg[idx];
    int t = blockIdx.x * 256 + threadIdx.x;
    int v = t >> 6, i = t & 63, w = threadIdx.x >> 6;
    float acc = 0.f;
    if (v < N) {
        int e = off[v], end = off[v + 1];
        for (; e + 1 < end; e += 2) {
            unsigned p0 = packed[e], p1 = packed[e + 1];
            float m0 = tAB[(p0 >> 17) * 64 + i];
            float m1 = tAB[(p1 >> 17) * 64 + i];
            if (MODE) {
                m0 += agg2[(long long)(p0 & 0x1FFFF) * 64 + i];
                m1 += agg2[(long long)(p1 & 0x1FFFF) * 64 + i];
            }
            acc += fmaxf(m0, 0.f) + fmaxf(m1, 0.f);
        }
        if (e < end) {
            unsigned p0 = packed[e];
            float m0 = tAB[(p0 >> 17) * 64 + i];
            if (MODE) m0 += agg2[(long long)(p0 & 0x1FFFF) * 64 + i];
            acc += fmaxf(m0, 0.f);
        }
    }
    if (MODE == 2) {
        if (v < N) out[(long long)v * 64 + i] = acc;
        return;
    }
    rowbuf[w][i] = acc;
    __syncthreads();
    if (v >= N) return;
    float s = 0.f;
#pragma unroll
    for (int k = 0; k < 64; ++k) s = fmaf(rowbuf[w][k], Ws[k * 64 + i], s);
    out[(long long)v * 64 + i] = s;
}

// batch is sorted: run-length accumulate, flush on mol change (few atomics).
__global__ void mol_pool_kernel(const float* __restrict__ ns, const int* __restrict__ batch,
                                float* __restrict__ mol, int N) {
    int wave = (blockIdx.x * blockDim.x + threadIdx.x) >> 6;
    int i = threadIdx.x & 63;
    int n0 = wave * 32;
    if (n0 >= N) return;
    int n1 = min(n0 + 32, N);
    int cur = batch[n0];
    float acc = 0.f;
    for (int n = n0; n < n1; ++n) {
        int b = batch[n];
        if (b != cur) { atomicAdd(&mol[(long long)cur * 64 + i], acc); acc = 0.f; cur = b; }
        acc += ns[(long long)n * 64 + i];
    }
    atomicAdd(&mol[(long long)cur * 64 + i], acc);
}

__global__ void head_kernel(const float* __restrict__ mol, const float* __restrict__ W1,
                            const float* __restrict__ b1, const float* __restrict__ W2,
                            const float* __restrict__ b2, float* __restrict__ out) {
    int g = blockIdx.x;
    int j = threadIdx.x;   // 0..127
    float s = b1[j];
#pragma unroll
    for (int k = 0; k < 64; ++k) s = fmaf(mol[g * 64 + k], W1[k * 128 + j], s);
    s = fmaxf(s, 0.0f) * W2[j];
    __shared__ float red[128];
    red[j] = s;
    __syncthreads();
    for (int off = 64; off > 0; off >>= 1) {
        if (j < off) red[j] += red[j + off];
        __syncthreads();
    }
    if (j == 0) out[g] = red[0] + b2[0];
}

extern "C" void kernel_launch(void* const* d_in, const int* in_sizes, int n_in,
                              void* d_out, int out_size, void* d_ws, size_t ws_size,
                              hipStream_t stream) {
    const int*   x          = (const int*)d_in[0];
    const int*   eattr      = (const int*)d_in[1];
    const int*   ei         = (const int*)d_in[2];
    const int*   batch      = (const int*)d_in[3];
    const float* atom_table = (const float*)d_in[4];
    const float* bond_table = (const float*)d_in[5];
    const float* Wi         = (const float*)d_in[6];
    const float* bi         = (const float*)d_in[7];
    const float* Wu         = (const float*)d_in[8];
    const float* bu         = (const float*)d_in[9];
    const float* W1         = (const float*)d_in[10];
    const float* b1         = (const float*)d_in[11];
    const float* W2         = (const float*)d_in[12];
    const float* b2         = (const float*)d_in[13];

    const int N = in_sizes[0];      // 100000
    const int E = in_sizes[1];      // 1600000
    const int M = out_size;         // 2048

    char* ws = (char*)d_ws;
    size_t off_b = 0;
    auto alloc = [&](size_t bytes) -> void* {
        void* p = ws + off_b;
        off_b = (off_b + bytes + 255) & ~(size_t)255;
        return p;
    };
    float*    bufA   = (float*)alloc((size_t)N * MSG * 4);
    float*    bufB   = (float*)alloc((size_t)N * MSG * 4);
    unsigned* packed = (unsigned*)alloc((size_t)E * 4);
    int*      cnt    = (int*)alloc((size_t)N * 4);
    int*      incl   = (int*)alloc((size_t)N * 4);
    int*      offs   = (int*)alloc((size_t)(N + 1) * 4);
    int*      cursor = (int*)alloc((size_t)N * 4);
    int*      bsum   = (int*)alloc(1024 * 4);
    float*    tABi   = (float*)alloc((size_t)NCOMBO * MSG * 4);
    float*    tABu   = (float*)alloc((size_t)NCOMBO * MSG * 4);
    float*    mol    = (float*)alloc((size_t)M * MSG * 4);
    (void)ws_size; (void)n_in;

    // Combined tables (atom@W + bond@W + bias), one row per (x, eattr) combo.
    build_tab_kernel<<<(NCOMBO * MSG + 255) / 256, 256, 0, stream>>>(atom_table, bond_table, Wi, bi, tABi);
    build_tab_kernel<<<(NCOMBO * MSG + 255) / 256, 256, 0, stream>>>(atom_table, bond_table, Wu, bu, tABu);

    // ---- CSR by dst ----
    const int nb = (N + 1023) / 1024;
    hipMemsetAsync(cnt, 0, (size_t)N * 4, stream);
    hist_kernel<<<(E + 255) / 256, 256, 0, stream>>>(ei, E, cnt);
    scan1_kernel<<<nb, 1024, 0, stream>>>(cnt, incl, bsum, N);
    scan2_kernel<<<1, 64, 0, stream>>>(bsum, nb);
    scan3_kernel<<<nb, 1024, 0, stream>>>(incl, bsum, offs, N);
    hipMemcpyAsync(cursor, offs, (size_t)N * 4, hipMemcpyDeviceToDevice, stream);
    scatter_kernel<<<(E + 255) / 256, 256, 0, stream>>>(ei, x, eattr, E, cursor, packed);

    // ---- message passes (gather form, fused node-GEMM epilogue) ----
    const int gblocks = (N + 3) / 4;   // 4 nodes (waves) per 256-thread block
    const float* Wagg = Wu + 80 * MSG;
    gather_kernel<0><<<gblocks, 256, 0, stream>>>(packed, offs, tABi, nullptr, Wagg, bufA, N);
    gather_kernel<1><<<gblocks, 256, 0, stream>>>(packed, offs, tABu, bufA, Wagg, bufB, N);
    gather_kernel<1><<<gblocks, 256, 0, stream>>>(packed, offs, tABu, bufB, Wagg, bufA, N);
    gather_kernel<1><<<gblocks, 256, 0, stream>>>(packed, offs, tABu, bufA, Wagg, bufB, N);
    gather_kernel<2><<<gblocks, 256, 0, stream>>>(packed, offs, tABu, bufB, Wagg, bufA, N);

    // ---- readout ----
    hipMemsetAsync(mol, 0, (size_t)M * MSG * 4, stream);
    mol_pool_kernel<<<((N + 31) / 32 * 64 + 255) / 256, 256, 0, stream>>>(bufA, batch, mol, N);
    head_kernel<<<M, 128, 0, stream>>>(mol, W1, b1, W2, b2, (float*)d_out);
}

// Round 3
// 544.195 us; speedup vs baseline: 4.6029x; 1.4876x over previous
//
#include <hip/hip_runtime.h>

#define MSG 64
#define NCOMBO 476   // 119 atom ids * 4 bond ids

// tAB[c][i] = bias[i] + atom[c>>2] @ W[0:64] + bond[c&3] @ W[64:80]   (W ld=64)
__global__ void build_tab_kernel(const float* __restrict__ atom, const float* __restrict__ bond,
                                 const float* __restrict__ W, const float* __restrict__ bias,
                                 float* __restrict__ tAB) {
    int t = blockIdx.x * blockDim.x + threadIdx.x;
    if (t >= NCOMBO * MSG) return;
    int i = t & 63, c = t >> 6, xa = c >> 2, ea = c & 3;
    float s = bias[i];
    for (int k = 0; k < 64; ++k) s = fmaf(atom[xa * 64 + k], W[k * 64 + i], s);
    for (int k = 0; k < 16; ++k) s = fmaf(bond[ea * 16 + k], W[(64 + k) * 64 + i], s);
    tAB[t] = s;
}

__global__ void hist_kernel(const int* __restrict__ ei, int E, int* __restrict__ cnt) {
    int e = blockIdx.x * blockDim.x + threadIdx.x;
    if (e < E) atomicAdd(&cnt[ei[E + e]], 1);
}

// block-level inclusive scan (1024/block) + block sums
__global__ void scan1_kernel(const int* __restrict__ cnt, int* __restrict__ incl,
                             int* __restrict__ bsum, int N) {
    int i = blockIdx.x * 1024 + threadIdx.x;
    int v = (i < N) ? cnt[i] : 0;
    int lane = threadIdx.x & 63, w = threadIdx.x >> 6;
    int s = v;
    for (int off = 1; off < 64; off <<= 1) { int t = __shfl_up(s, off); if (lane >= off) s += t; }
    __shared__ int wsum[16];
    if (lane == 63) wsum[w] = s;
    __syncthreads();
    if (w == 0 && lane < 16) {
        int t = wsum[lane];
        for (int off = 1; off < 16; off <<= 1) { int u = __shfl_up(t, off); if (lane >= off) t += u; }
        wsum[lane] = t;
    }
    __syncthreads();
    if (w > 0) s += wsum[w - 1];
    if (i < N) incl[i] = s;
    if (threadIdx.x == 1023) bsum[blockIdx.x] = s;
}

__global__ void scan2_kernel(int* __restrict__ bsum, int nb) {
    if (threadIdx.x == 0 && blockIdx.x == 0) {
        int run = 0;
        for (int b = 0; b < nb; ++b) { int t = bsum[b]; bsum[b] = run; run += t; }
    }
}

__global__ void scan3_kernel(const int* __restrict__ incl, const int* __restrict__ bsum,
                             int* __restrict__ off, int N) {
    int i = blockIdx.x * 1024 + threadIdx.x;
    if (i < N) off[i + 1] = incl[i] + bsum[blockIdx.x];
    if (i == 0) off[0] = 0;
}

// packed[pos] = src | combo<<17, pos claimed via cursor (cursor pre-loaded with CSR offsets)
__global__ void scatter_kernel(const int* __restrict__ ei, const int* __restrict__ x,
                               const int* __restrict__ eattr, int E,
                               int* __restrict__ cursor, unsigned* __restrict__ packed) {
    int e = blockIdx.x * blockDim.x + threadIdx.x;
    if (e >= E) return;
    int s = ei[e], d = ei[E + e];
    int p = atomicAdd(&cursor[d], 1);
    packed[p] = (unsigned)s | ((unsigned)(x[s] * 4 + eattr[e]) << 17);
}

// 16 lanes per node (float4 per lane), 16 nodes per 256-thread block.
// acc = sum_{in-edges} relu(tAB[combo] + agg2[src]).
// MODE 0: no agg2, fused epilogue GEMM; MODE 1: agg2 + fused GEMM; MODE 2: agg2, raw out.
template <int MODE>
__global__ __launch_bounds__(256) void gather_kernel(
    const unsigned* __restrict__ packed, const int* __restrict__ off,
    const float* __restrict__ tAB, const float* __restrict__ agg2,
    const float* __restrict__ Wagg, float* __restrict__ out, int N)
{
    __shared__ float Ws[64 * 64];
    __shared__ float rowbuf[16][68];   // stride 68 de-conflicts per-group broadcast
    if (MODE < 2)
        for (int idx = threadIdx.x; idx < 64 * 64; idx += 256) Ws[idx] = Wagg[idx];
    int t = blockIdx.x * 256 + threadIdx.x;
    int v = t >> 4;                    // node
    int j = threadIdx.x & 15;          // feature quad
    int w = threadIdx.x >> 4;          // group in block
    const float4* tAB4 = (const float4*)tAB;
    const float4* agg4 = (const float4*)agg2;
    float ax = 0.f, ay = 0.f, az = 0.f, aw = 0.f;
    if (v < N) {
        int e = off[v], end = off[v + 1];
        for (; e + 1 < end; e += 2) {
            unsigned p0 = packed[e], p1 = packed[e + 1];
            float4 m0 = tAB4[(p0 >> 17) * 16 + j];
            float4 m1 = tAB4[(p1 >> 17) * 16 + j];
            if (MODE) {
                float4 a0 = agg4[(p0 & 0x1FFFFu) * 16 + j];
                float4 a1 = agg4[(p1 & 0x1FFFFu) * 16 + j];
                m0.x += a0.x; m0.y += a0.y; m0.z += a0.z; m0.w += a0.w;
                m1.x += a1.x; m1.y += a1.y; m1.z += a1.z; m1.w += a1.w;
            }
            ax += fmaxf(m0.x, 0.f) + fmaxf(m1.x, 0.f);
            ay += fmaxf(m0.y, 0.f) + fmaxf(m1.y, 0.f);
            az += fmaxf(m0.z, 0.f) + fmaxf(m1.z, 0.f);
            aw += fmaxf(m0.w, 0.f) + fmaxf(m1.w, 0.f);
        }
        if (e < end) {
            unsigned p0 = packed[e];
            float4 m0 = tAB4[(p0 >> 17) * 16 + j];
            if (MODE) {
                float4 a0 = agg4[(p0 & 0x1FFFFu) * 16 + j];
                m0.x += a0.x; m0.y += a0.y; m0.z += a0.z; m0.w += a0.w;
            }
            ax += fmaxf(m0.x, 0.f);
            ay += fmaxf(m0.y, 0.f);
            az += fmaxf(m0.z, 0.f);
            aw += fmaxf(m0.w, 0.f);
        }
    }
    if (MODE == 2) {
        if (v < N) {
            float4 o; o.x = ax; o.y = ay; o.z = az; o.w = aw;
            ((float4*)out)[(long long)v * 16 + j] = o;
        }
        return;
    }
    rowbuf[w][j * 4 + 0] = ax;
    rowbuf[w][j * 4 + 1] = ay;
    rowbuf[w][j * 4 + 2] = az;
    rowbuf[w][j * 4 + 3] = aw;
    __syncthreads();
    if (v >= N) return;
    const float4* Ws4 = (const float4*)Ws;
    float sx = 0.f, sy = 0.f, sz = 0.f, sw = 0.f;
#pragma unroll
    for (int k = 0; k < 64; ++k) {
        float r = rowbuf[w][k];
        float4 wv = Ws4[k * 16 + j];
        sx = fmaf(r, wv.x, sx);
        sy = fmaf(r, wv.y, sy);
        sz = fmaf(r, wv.z, sz);
        sw = fmaf(r, wv.w, sw);
    }
    float4 o; o.x = sx; o.y = sy; o.z = sz; o.w = sw;
    ((float4*)out)[(long long)v * 16 + j] = o;
}

// batch is sorted: run-length accumulate, flush on mol change. 16 lanes x float4 per 32-node chunk.
__global__ void mol_pool_kernel(const float* __restrict__ ns, const int* __restrict__ batch,
                                float* __restrict__ mol, int N) {
    int g = (blockIdx.x * blockDim.x + threadIdx.x) >> 4;
    int j = threadIdx.x & 15;
    int n0 = g * 32;
    if (n0 >= N) return;
    int n1 = min(n0 + 32, N);
    const float4* ns4 = (const float4*)ns;
    int cur = batch[n0];
    float ax = 0.f, ay = 0.f, az = 0.f, aw = 0.f;
    for (int n = n0; n < n1; ++n) {
        int b = batch[n];
        if (b != cur) {
            float* mp = &mol[(long long)cur * 64 + j * 4];
            atomicAdd(mp + 0, ax); atomicAdd(mp + 1, ay);
            atomicAdd(mp + 2, az); atomicAdd(mp + 3, aw);
            ax = ay = az = aw = 0.f; cur = b;
        }
        float4 vv = ns4[(long long)n * 16 + j];
        ax += vv.x; ay += vv.y; az += vv.z; aw += vv.w;
    }
    float* mp = &mol[(long long)cur * 64 + j * 4];
    atomicAdd(mp + 0, ax); atomicAdd(mp + 1, ay);
    atomicAdd(mp + 2, az); atomicAdd(mp + 3, aw);
}

__global__ void head_kernel(const float* __restrict__ mol, const float* __restrict__ W1,
                            const float* __restrict__ b1, const float* __restrict__ W2,
                            const float* __restrict__ b2, float* __restrict__ out) {
    int g = blockIdx.x;
    int j = threadIdx.x;   // 0..127
    float s = b1[j];
#pragma unroll
    for (int k = 0; k < 64; ++k) s = fmaf(mol[g * 64 + k], W1[k * 128 + j], s);
    s = fmaxf(s, 0.0f) * W2[j];
    __shared__ float red[128];
    red[j] = s;
    __syncthreads();
    for (int off = 64; off > 0; off >>= 1) {
        if (j < off) red[j] += red[j + off];
        __syncthreads();
    }
    if (j == 0) out[g] = red[0] + b2[0];
}

extern "C" void kernel_launch(void* const* d_in, const int* in_sizes, int n_in,
                              void* d_out, int out_size, void* d_ws, size_t ws_size,
                              hipStream_t stream) {
    const int*   x          = (const int*)d_in[0];
    const int*   eattr      = (const int*)d_in[1];
    const int*   ei         = (const int*)d_in[2];
    const int*   batch      = (const int*)d_in[3];
    const float* atom_table = (const float*)d_in[4];
    const float* bond_table = (const float*)d_in[5];
    const float* Wi         = (const float*)d_in[6];
    const float* bi         = (const float*)d_in[7];
    const float* Wu         = (const float*)d_in[8];
    const float* bu         = (const float*)d_in[9];
    const float* W1         = (const float*)d_in[10];
    const float* b1         = (const float*)d_in[11];
    const float* W2         = (const float*)d_in[12];
    const float* b2         = (const float*)d_in[13];

    const int N = in_sizes[0];      // 100000
    const int E = in_sizes[1];      // 1600000
    const int M = out_size;         // 2048

    char* ws = (char*)d_ws;
    size_t off_b = 0;
    auto alloc = [&](size_t bytes) -> void* {
        void* p = ws + off_b;
        off_b = (off_b + bytes + 255) & ~(size_t)255;
        return p;
    };
    float*    bufA   = (float*)alloc((size_t)N * MSG * 4);
    float*    bufB   = (float*)alloc((size_t)N * MSG * 4);
    unsigned* packed = (unsigned*)alloc((size_t)E * 4);
    int*      cnt    = (int*)alloc((size_t)N * 4);
    int*      incl   = (int*)alloc((size_t)N * 4);
    int*      offs   = (int*)alloc((size_t)(N + 1) * 4);
    int*      cursor = (int*)alloc((size_t)N * 4);
    int*      bsum   = (int*)alloc(1024 * 4);
    float*    tABi   = (float*)alloc((size_t)NCOMBO * MSG * 4);
    float*    tABu   = (float*)alloc((size_t)NCOMBO * MSG * 4);
    float*    mol    = (float*)alloc((size_t)M * MSG * 4);
    (void)ws_size; (void)n_in;

    // Combined tables (atom@W + bond@W + bias), one row per (x, eattr) combo.
    build_tab_kernel<<<(NCOMBO * MSG + 255) / 256, 256, 0, stream>>>(atom_table, bond_table, Wi, bi, tABi);
    build_tab_kernel<<<(NCOMBO * MSG + 255) / 256, 256, 0, stream>>>(atom_table, bond_table, Wu, bu, tABu);

    // ---- CSR by dst ----
    const int nb = (N + 1023) / 1024;
    hipMemsetAsync(cnt, 0, (size_t)N * 4, stream);
    hist_kernel<<<(E + 255) / 256, 256, 0, stream>>>(ei, E, cnt);
    scan1_kernel<<<nb, 1024, 0, stream>>>(cnt, incl, bsum, N);
    scan2_kernel<<<1, 64, 0, stream>>>(bsum, nb);
    scan3_kernel<<<nb, 1024, 0, stream>>>(incl, bsum, offs, N);
    hipMemcpyAsync(cursor, offs, (size_t)N * 4, hipMemcpyDeviceToDevice, stream);
    scatter_kernel<<<(E + 255) / 256, 256, 0, stream>>>(ei, x, eattr, E, cursor, packed);

    // ---- message passes (gather form, fused node-GEMM epilogue) ----
    const int gblocks = (int)(((long long)N * 16 + 255) / 256);
    const float* Wagg = Wu + 80 * MSG;
    gather_kernel<0><<<gblocks, 256, 0, stream>>>(packed, offs, tABi, nullptr, Wagg, bufA, N);
    gather_kernel<1><<<gblocks, 256, 0, stream>>>(packed, offs, tABu, bufA, Wagg, bufB, N);
    gather_kernel<1><<<gblocks, 256, 0, stream>>>(packed, offs, tABu, bufB, Wagg, bufA, N);
    gather_kernel<1><<<gblocks, 256, 0, stream>>>(packed, offs, tABu, bufA, Wagg, bufB, N);
    gather_kernel<2><<<gblocks, 256, 0, stream>>>(packed, offs, tABu, bufB, Wagg, bufA, N);

    // ---- readout ----
    hipMemsetAsync(mol, 0, (size_t)M * MSG * 4, stream);
    mol_pool_kernel<<<(((N + 31) / 32) * 16 + 255) / 256, 256, 0, stream>>>(bufA, batch, mol, N);
    head_kernel<<<M, 128, 0, stream>>>(mol, W1, b1, W2, b2, (float*)d_out);
}